// Round 15
// baseline (79.549 us; speedup 1.0000x reference)
//
#include <hip/hip_runtime.h>
#include <math.h>

#define N_Q     16384
#define DDIM    512
#define M_SLOTS 2048
#define EPSN    1e-12f
#define TEMPU   1e-5f
#define KSCALE  25.4f                    // int8 scale for keys (clips at ~5 sigma)
#define QSCALE  127.0f
#define INV_S   (1.0f / (127.0f * 25.4f))
#define NZBLK   73                       // zero-fill blocks appended to k_prep (73*2048B)
#define BCAP    32                       // bucket capacity per slot (Poisson(8): P(>32)~1e-9)

typedef unsigned int u32;
typedef unsigned long long u64;
typedef __attribute__((ext_vector_type(4))) int i32x4;

// ---------- helpers ----------
__device__ __forceinline__ void gld_lds16(const void* g, void* l) {
    __builtin_amdgcn_global_load_lds(
        (const __attribute__((address_space(1))) u32*)(g),
        (__attribute__((address_space(3))) u32*)(l), 16, 0, 0);
}
__device__ __forceinline__ float block_reduce_sum_128(float v, float* sred, int t) {
    #pragma unroll
    for (int o = 32; o > 0; o >>= 1) v += __shfl_down(v, o, 64);
    if ((t & 63) == 0) sred[t >> 6] = v;
    __syncthreads();
    return sred[0] + sred[1];
}
__device__ __forceinline__ char q8(float x, float s) {
    int v = __float2int_rn(x * s);
    v = v < -127 ? -127 : (v > 127 ? 127 : v);
    return (char)v;
}

// ---------- kernel 1: normalize+quantize queries / keys->i8 / zero-fill scratch ----------
__global__ __launch_bounds__(128) void k_prep(const float* __restrict__ q,
                                              const float* __restrict__ keys,
                                              char* __restrict__ qi8,
                                              char* __restrict__ ki8,
                                              float4* __restrict__ zbase) {
    __shared__ float sred[2];
    int b = blockIdx.x;
    int t = threadIdx.x;
    if (b < N_Q) {
        float4 v = ((const float4*)(q + (size_t)b * DDIM))[t];
        float ss = v.x * v.x + v.y * v.y + v.z * v.z + v.w * v.w;
        ss = block_reduce_sum_128(ss, sred, t);
        float s = QSCALE / fmaxf(sqrtf(ss), EPSN);
        char4 o;
        o.x = q8(v.x, s);
        o.y = q8(v.y, s);
        o.z = q8(v.z, s);
        o.w = q8(v.w, s);
        ((char4*)(qi8 + (size_t)b * DDIM))[t] = o;
    } else if (b < N_Q + M_SLOTS) {
        int r = b - N_Q;
        float4 v = ((const float4*)(keys + (size_t)r * DDIM))[t];
        char4 o;
        o.x = q8(v.x, KSCALE);
        o.y = q8(v.y, KSCALE);
        o.z = q8(v.z, KSCALE);
        o.w = q8(v.w, KSCALE);
        ((char4*)(ki8 + (size_t)r * DDIM))[t] = o;
    } else {
        int idx = (b - (N_Q + M_SLOTS)) * 128 + t;
        zbase[idx] = make_float4(0.f, 0.f, 0.f, 0.f);
    }
}

// ---------- kernel 2: i8 MFMA score GEMM — 256x256, 8-wave, fine-phase schedule ----------
// m201-template port (i8): BM=BN=256, BK=64, 8 K-tiles, 512 thr / 8 waves (2x4).
// Wave tile 128x64 (8 m-frags x 4 n-frags). LDS 2buf x 2half x 8KB per operand
// = 64KB -> 2 blocks/CU, grid 512 = exactly 2/CU (one residency round).
// Per phase: {ds_read a-pair (+4 b at p0), 1 gld_lds stage, barrier,
// lgkmcnt(0), setprio(1), 8 MFMA, setprio(0), barrier}. Boundary: vmcnt(2)
// (counted - the 2 newest B-units stay in flight; never drain in-loop).
// Stage windows (paper-verified): A(t+1) -> idle buf at p0/p1; B(t+2) -> live
// buf halves at p2/p3 (B consumed into regs at p0; overwrite is post-barrier).
// Swizzle (r11, measured conflict-free): write chunk (t&3)^((t>>3)&3),
// read chunk kc^((lr>>1)&3).
__global__ __launch_bounds__(512) void k_score(const char* __restrict__ qi8,
                                               const char* __restrict__ ki8,
                                               u64* __restrict__ rowpack,
                                               u32* __restrict__ colmax) {
    __shared__ char sA[2][2][128 * 64];   // [buf][half] 8KB units, 32KB
    __shared__ char sB[2][2][128 * 64];   // 32KB

    int t = threadIdx.x;
    int lane = t & 63;
    int wid = t >> 6;            // 0..7
    int wr = wid >> 2;           // 0..1: A half (output rows wr*128..+128)
    int wc = wid & 3;            // 0..3: output cols wc*64..+64; B half = wc>>1
    int lr = lane & 15;          // frag row (A) / col (B)
    int kc = lane >> 4;          // k-chunk 0..3 (16 i8 each)

    int j0 = blockIdx.x * 256;   // slot block
    int n0 = blockIdx.y * 256;   // query block

    int srow = t >> 2;                              // staging row 0..127
    int gcol = 16 * ((t & 3) ^ ((t >> 3) & 3));     // inverse-swizzled chunk
    int roff = 16 * (kc ^ ((lr >> 1) & 3));         // read-side swizzle

    const char* baseA = qi8 + (size_t)(n0 + srow) * DDIM + gcol;
    const char* baseB = ki8 + (size_t)(j0 + srow) * DDIM + gcol;

    // stage unit: half h of operand tile tt (1 gld_lds16 per thread = 8KB)
#define SA(tt, h) gld_lds16(baseA + (size_t)(h) * 128 * DDIM + (tt) * 64, \
                            &sA[(tt) & 1][h][t * 16])
#define SB(tt, h) gld_lds16(baseB + (size_t)(h) * 128 * DDIM + (tt) * 64, \
                            &sB[(tt) & 1][h][t * 16])

    i32x4 acc[8][4] = {};
    i32x4 b[4];

    // prologue: T0 complete + B of T1 (6 units); wait all but newest 2
    SA(0, 0); SA(0, 1); SB(0, 0); SB(0, 1); SB(1, 0); SB(1, 1);
    asm volatile("s_waitcnt vmcnt(2)" ::: "memory");
    __builtin_amdgcn_s_barrier();
    __builtin_amdgcn_sched_barrier(0);

    #pragma unroll
    for (int tt = 0; tt < 8; ++tt) {
        const int buf = tt & 1;
        #pragma unroll
        for (int p = 0; p < 4; ++p) {
            // --- phase reads (ds_read) ---
            if (p == 0) {
                #pragma unroll
                for (int j = 0; j < 4; ++j)
                    b[j] = *(const i32x4*)&sB[buf][wc >> 1]
                               [((wc & 1) * 64 + j * 16 + lr) * 64 + roff];
            }
            i32x4 a0 = *(const i32x4*)&sA[buf][wr][((2 * p) * 16 + lr) * 64 + roff];
            i32x4 a1 = *(const i32x4*)&sA[buf][wr][((2 * p + 1) * 16 + lr) * 64 + roff];
            // --- stage issue (1 unit/phase; windows verified) ---
            if      (p == 0) { if (tt < 7) SA(tt + 1, 0); }
            else if (p == 1) { if (tt < 7) SA(tt + 1, 1); }
            else if (p == 2) { if (tt < 6) SB(tt + 2, 0); }
            else             { if (tt < 6) SB(tt + 2, 1); }
            // --- align, complete reads, MFMA cluster ---
            __builtin_amdgcn_s_barrier();
            asm volatile("s_waitcnt lgkmcnt(0)" ::: "memory");
            __builtin_amdgcn_sched_barrier(0);
            __builtin_amdgcn_s_setprio(1);
            #pragma unroll
            for (int j = 0; j < 4; ++j) {
                acc[2 * p][j] =
                    __builtin_amdgcn_mfma_i32_16x16x64_i8(a0, b[j], acc[2 * p][j], 0, 0, 0);
                acc[2 * p + 1][j] =
                    __builtin_amdgcn_mfma_i32_16x16x64_i8(a1, b[j], acc[2 * p + 1][j], 0, 0, 0);
            }
            __builtin_amdgcn_s_setprio(0);
            // --- K-tile boundary: counted wait (next tile's units landed) ---
            if (p == 3) {
                if (tt < 6)       asm volatile("s_waitcnt vmcnt(2)" ::: "memory");
                else if (tt == 6) asm volatile("s_waitcnt vmcnt(0)" ::: "memory");
            }
            if (!(tt == 7 && p == 3)) {
                __builtin_amdgcn_s_barrier();
                __builtin_amdgcn_sched_barrier(0);
            }
        }
    }
#undef SA
#undef SB

    // ---- fused epilogue (int scores) ----
    // C/D layout per 16x16 frag: col = lr, row = kc*4 + r
    #pragma unroll
    for (int f = 0; f < 8; ++f) {
        #pragma unroll
        for (int r = 0; r < 4; ++r) {
            int v = acc[f][0][r];
            int c = j0 + wc * 64 + lr;
            #pragma unroll
            for (int j = 1; j < 4; ++j) {
                int vj = acc[f][j][r];
                int cj = j0 + wc * 64 + j * 16 + lr;
                if (vj > v) { v = vj; c = cj; }
            }
            #pragma unroll
            for (int off = 1; off < 16; off <<= 1) {
                int ov = __shfl_xor(v, off, 64);
                int oc = __shfl_xor(c, off, 64);
                if (ov > v || (ov == v && oc < c)) { v = ov; c = oc; }
            }
            if (lr == 0) {
                int grow = n0 + wr * 128 + f * 16 + kc * 4 + r;
                u64 pk = ((u64)(u32)(v ^ 0x80000000) << 32) | (u64)(~(u32)c);
                atomicMax(rowpack + grow, pk);
            }
        }
    }
    #pragma unroll
    for (int j = 0; j < 4; ++j) {
        int m = acc[0][j][0];
        #pragma unroll
        for (int f = 0; f < 8; ++f)
            #pragma unroll
            for (int r = 0; r < 4; ++r) m = max(m, acc[f][j][r]);
        m = max(m, __shfl_xor(m, 16, 64));
        m = max(m, __shfl_xor(m, 32, 64));
        if (kc == 0) atomicMax(colmax + j0 + wc * 64 + j * 16 + lr,
                               (u32)m ^ 0x80000000u);   // biased: zero-init == -inf
    }
}

// ---------- kernel 3: bucket-claim fill ----------
__global__ __launch_bounds__(256) void k_fill(const u64* __restrict__ rowpack,
                                              const u32* __restrict__ colmax,
                                              u32* __restrict__ cur,
                                              u32* __restrict__ bperm,
                                              float* __restrict__ bw,
                                              u32* __restrict__ ovf_cnt,
                                              u32* __restrict__ ovf_n,
                                              float* __restrict__ ovf_w) {
    int n = blockIdx.x * 256 + threadIdx.x;
    u64 p = rowpack[n];
    int vi = (int)(((u32)(p >> 32)) ^ 0x80000000u);
    int g = (int)(~(u32)(p & 0xFFFFFFFFull));
    int cm = (int)(colmax[g] ^ 0x80000000u);
    float w = expf((float)(vi - cm) * INV_S);   // <= 1
    u32 pos = atomicAdd(cur + g, 1u);
    if (pos < BCAP) {
        bperm[g * BCAP + pos] = (u32)n;
        bw[g * BCAP + pos] = w;
    } else {
        u32 o = atomicAdd(ovf_cnt, 1u);
        ovf_n[o] = ((u32)g << 16) | (u32)n;
        ovf_w[o] = w;
    }
}

// ---------- kernel 4: gather + final normalize (fused) ----------
__global__ __launch_bounds__(128) void k_gather_final(const char* __restrict__ qi8,
                                                      const u32* __restrict__ cur,
                                                      const u32* __restrict__ bperm,
                                                      const float* __restrict__ bw,
                                                      const u32* __restrict__ ovf_cnt,
                                                      const u32* __restrict__ ovf_n,
                                                      const float* __restrict__ ovf_w,
                                                      const float* __restrict__ keys,
                                                      float* __restrict__ out) {
    __shared__ float sred[2];
    int j = blockIdx.x;
    int t = threadIdx.x;
    u32 c = cur[j];
    u32 cnt = c < BCAP ? c : BCAP;
    float ax = 0.f, ay = 0.f, az = 0.f, aw = 0.f;
    for (u32 i = 0; i < cnt; ++i) {
        u32 n = bperm[j * BCAP + i];
        float wq = bw[j * BCAP + i] * (1.0f / 127.0f);
        char4 q4 = ((const char4*)(qi8 + (size_t)n * DDIM))[t];
        ax = fmaf(wq, (float)q4.x, ax);
        ay = fmaf(wq, (float)q4.y, ay);
        az = fmaf(wq, (float)q4.z, az);
        aw = fmaf(wq, (float)q4.w, aw);
    }
    if (c > BCAP) {                      // rare overflow path (wave-uniform)
        u32 oc = *ovf_cnt;
        for (u32 i = 0; i < oc; ++i) {
            u32 e = ovf_n[i];
            if ((e >> 16) == (u32)j) {
                u32 n = e & 0xFFFFu;
                float wq = ovf_w[i] * (1.0f / 127.0f);
                char4 q4 = ((const char4*)(qi8 + (size_t)n * DDIM))[t];
                ax = fmaf(wq, (float)q4.x, ax);
                ay = fmaf(wq, (float)q4.y, ay);
                az = fmaf(wq, (float)q4.z, az);
                aw = fmaf(wq, (float)q4.w, aw);
            }
        }
    }
    float4 k4 = ((const float4*)(keys + (size_t)j * DDIM))[t];
    float4 v;
    v.x = fmaf(TEMPU, ax, k4.x);
    v.y = fmaf(TEMPU, ay, k4.y);
    v.z = fmaf(TEMPU, az, k4.z);
    v.w = fmaf(TEMPU, aw, k4.w);
    float ss = v.x * v.x + v.y * v.y + v.z * v.z + v.w * v.w;
    ss = block_reduce_sum_128(ss, sred, t);
    float inv = 1.0f / fmaxf(sqrtf(ss), EPSN);
    v.x *= inv; v.y *= inv; v.z *= inv; v.w *= inv;
    ((float4*)(out + (size_t)j * DDIM))[t] = v;
}

// ---------- launch ----------
extern "C" void kernel_launch(void* const* d_in, const int* in_sizes, int n_in,
                              void* d_out, int out_size, void* d_ws, size_t ws_size,
                              hipStream_t stream) {
    const float* query = (const float*)d_in[0];   // [16384, 512] f32
    const float* keys  = (const float*)d_in[1];   // [2048, 512] f32
    float* out = (float*)d_out;                   // [2048, 512] f32

    char* ws = (char*)d_ws;
    const size_t OFF_QI8   = 0;                        //  8,388,608 B
    const size_t OFF_ROW   = 8388608;                  //    131,072 B  rowpack u64[16384]
    const size_t OFF_CMAX  = OFF_ROW + 131072;         //      8,192 B  colmax u32 biased
    const size_t OFF_CUR   = OFF_CMAX + 8192;          //      8,192 B  cur u32[2048]
    const size_t OFF_OVFC  = OFF_CUR + 8192;           //      2,048 B  ovf_cnt (padded)
    const size_t OFF_BPERM = OFF_OVFC + 2048;          //    262,144 B  bperm u32[2048][32]
    const size_t OFF_BW    = OFF_BPERM + 262144;       //    262,144 B  bw f32[2048][32]
    const size_t OFF_OVFN  = OFF_BW + 262144;          //     65,536 B  ovf_n
    const size_t OFF_OVFW  = OFF_OVFN + 65536;         //     65,536 B  ovf_w
    const size_t OFF_KI8   = OFF_OVFW + 65536;         //  1,048,576 B

    char*   qi8    = ws + OFF_QI8;
    u64*    rowpack= (u64*)(ws + OFF_ROW);
    u32*    cmax   = (u32*)(ws + OFF_CMAX);
    u32*    cur    = (u32*)(ws + OFF_CUR);
    u32*    ovfc   = (u32*)(ws + OFF_OVFC);
    u32*    bperm  = (u32*)(ws + OFF_BPERM);
    float*  bw     = (float*)(ws + OFF_BW);
    u32*    ovfn   = (u32*)(ws + OFF_OVFN);
    float*  ovfw   = (float*)(ws + OFF_OVFW);
    char*   ki8    = ws + OFF_KI8;

    // k_prep zero-fills rowpack+colmax+cur+ovf_cnt (last NZBLK blocks)
    k_prep<<<N_Q + M_SLOTS + NZBLK, 128, 0, stream>>>(query, keys, qi8, ki8,
                                                      (float4*)(ws + OFF_ROW));

    dim3 g2(M_SLOTS / 256, N_Q / 256);  // 8 x 64 = 512 blocks = 2/CU
    k_score<<<g2, 512, 0, stream>>>(qi8, ki8, rowpack, cmax);

    k_fill<<<N_Q / 256, 256, 0, stream>>>(rowpack, cmax, cur, bperm, bw,
                                          ovfc, ovfn, ovfw);
    k_gather_final<<<M_SLOTS, 128, 0, stream>>>(qi8, cur, bperm, bw,
                                                ovfc, ovfn, ovfw, keys, out);
}